// Round 1
// baseline (9.737 us; speedup 1.0000x reference)
//
#include <hip/hip_runtime.h>

// QuantumAttentionHead: 10-wire circuit of RX gates only, starting from |0..0>.
// Product state ⇒ out[b,i] = cos(token[b,i] + thetas[i]).

#define QAH_BATCH 16384
#define QAH_NW    10

__global__ __launch_bounds__(256) void QuantumAttentionHead_65481071404559_kernel(
    const float* __restrict__ token,   // (BATCH, NW)
    const float* __restrict__ thetas,  // (NW,)
    float* __restrict__ out)           // (BATCH, NW)
{
    __shared__ float th[QAH_NW];
    if (threadIdx.x < QAH_NW) th[threadIdx.x] = thetas[threadIdx.x];
    __syncthreads();

    const int total = QAH_BATCH * QAH_NW;
    int idx = blockIdx.x * blockDim.x + threadIdx.x;
    if (idx < total) {
        int w = idx % QAH_NW;
        out[idx] = cosf(token[idx] + th[w]);
    }
}

extern "C" void kernel_launch(void* const* d_in, const int* in_sizes, int n_in,
                              void* d_out, int out_size, void* d_ws, size_t ws_size,
                              hipStream_t stream) {
    const float* token  = (const float*)d_in[0];
    const float* thetas = (const float*)d_in[1];
    float* out = (float*)d_out;

    const int total = QAH_BATCH * QAH_NW;
    const int block = 256;
    const int grid = (total + block - 1) / block;
    QuantumAttentionHead_65481071404559_kernel<<<grid, block, 0, stream>>>(token, thetas, out);
}

// Round 2
// 9.582 us; speedup vs baseline: 1.0162x; 1.0162x over previous
//
#include <hip/hip_runtime.h>

// QuantumAttentionHead: 10-wire circuit of RX-only gates on |0..0> ⇒ product
// state ⇒ out[b,i] = cos(token[b,i] + thetas[i]).
// Elementwise, 1.3 MB total traffic, launch-overhead dominated.

#define QAH_BATCH 16384
#define QAH_NW    10
#define QAH_TOTAL (QAH_BATCH * QAH_NW)   // 163840, divisible by 4

__global__ __launch_bounds__(256) void QuantumAttentionHead_65481071404559_kernel(
    const float4* __restrict__ token4,  // (BATCH*NW/4,)
    const float* __restrict__ thetas,   // (NW,)
    float4* __restrict__ out4)          // (BATCH*NW/4,)
{
    // 10 thetas: read them all into registers (L1/L2-resident, broadcast).
    float th[QAH_NW];
#pragma unroll
    for (int i = 0; i < QAH_NW; ++i) th[i] = thetas[i];

    int idx = blockIdx.x * blockDim.x + threadIdx.x;   // float4 index
    if (idx < QAH_TOTAL / 4) {
        float4 t = token4[idx];
        int base = idx * 4;
        int w = base % QAH_NW;
        float4 r;
        r.x = cosf(t.x + th[w]);            w = (w + 1 == QAH_NW) ? 0 : w + 1;
        r.y = cosf(t.y + th[w]);            w = (w + 1 == QAH_NW) ? 0 : w + 1;
        r.z = cosf(t.z + th[w]);            w = (w + 1 == QAH_NW) ? 0 : w + 1;
        r.w = cosf(t.w + th[w]);
        out4[idx] = r;
    }
}

extern "C" void kernel_launch(void* const* d_in, const int* in_sizes, int n_in,
                              void* d_out, int out_size, void* d_ws, size_t ws_size,
                              hipStream_t stream) {
    const float4* token4 = (const float4*)d_in[0];
    const float*  thetas = (const float*)d_in[1];
    float4* out4 = (float4*)d_out;

    const int n4 = QAH_TOTAL / 4;          // 40960
    const int block = 256;
    const int grid = (n4 + block - 1) / block;  // 160
    QuantumAttentionHead_65481071404559_kernel<<<grid, block, 0, stream>>>(token4, thetas, out4);
}